// Round 2
// baseline (242.994 us; speedup 1.0000x reference)
//
#include <hip/hip_runtime.h>
#include <hip/hip_bf16.h>

#define EPSF 1e-5f

// ---------------- K1: comp = relu(bn(conv1x1(x))) ----------------
// x [2,256,4096] fp32 -> comp [2,64,4096] fp32. Thread handles 8 output channels.
__global__ void k1_comp(const float* __restrict__ x, const float* __restrict__ w,
                        const float* __restrict__ gamma, const float* __restrict__ beta,
                        const float* __restrict__ mean, const float* __restrict__ var,
                        float* __restrict__ comp) {
    int t = blockIdx.x * 256 + threadIdx.x;     // 65536 threads total
    int p  = t & 4095;
    int mq = (t >> 12) & 7;
    int b  = t >> 15;
    int m0 = mq * 8;
    const float* xb = x + b * (256 * 4096) + p;
    float acc[8] = {0.f, 0.f, 0.f, 0.f, 0.f, 0.f, 0.f, 0.f};
    for (int c = 0; c < 256; ++c) {
        float xv = xb[c << 12];
        #pragma unroll
        for (int m = 0; m < 8; ++m)
            acc[m] += xv * w[(m0 + m) * 256 + c];
    }
    #pragma unroll
    for (int m = 0; m < 8; ++m) {
        int mo = m0 + m;
        float s = gamma[mo] * rsqrtf(var[mo] + EPSF);
        float r = acc[m] * s + (beta[mo] - mean[mo] * s);
        comp[(b * 64 + mo) * 4096 + p] = fmaxf(r, 0.f);
    }
}

// ---------------- K2: enc = bn(conv3x3(comp)) ----------------
// comp [2,64,64,64] fp32 -> enc [2,100,64,64] fp32. Thread handles o and o+50.
__global__ void k2_enc(const float* __restrict__ comp, const float* __restrict__ w,
                       const float* __restrict__ gamma, const float* __restrict__ beta,
                       const float* __restrict__ mean, const float* __restrict__ var,
                       float* __restrict__ enc) {
    int t = blockIdx.x * 256 + threadIdx.x;     // 409600 threads total
    int xq = t & 63;
    int y  = (t >> 6) & 63;
    int oq = (t >> 12) % 50;
    int b  = t / 204800;
    int o0 = oq, o1 = oq + 50;
    const float* cb = comp + b * (64 * 4096);
    const float* wp0 = w + o0 * 576;
    const float* wp1 = w + o1 * 576;
    float a0 = 0.f, a1 = 0.f;
    for (int ic = 0; ic < 64; ++ic) {
        const float* cc = cb + (ic << 12);
        float w0v[9], w1v[9];
        #pragma unroll
        for (int q = 0; q < 9; ++q) {
            w0v[q] = wp0[ic * 9 + q];
            w1v[q] = wp1[ic * 9 + q];
        }
        #pragma unroll
        for (int dy = 0; dy < 3; ++dy) {
            int row = y + dy - 1;
            if (row < 0 || row > 63) continue;
            const float* rp = cc + (row << 6);
            #pragma unroll
            for (int dx = 0; dx < 3; ++dx) {
                int col = xq + dx - 1;
                if (col >= 0 && col <= 63) {
                    float v = rp[col];
                    a0 += v * w0v[dy * 3 + dx];
                    a1 += v * w1v[dy * 3 + dx];
                }
            }
        }
    }
    float s0 = gamma[o0] * rsqrtf(var[o0] + EPSF);
    float s1 = gamma[o1] * rsqrtf(var[o1] + EPSF);
    enc[(b * 100 + o0) * 4096 + (y << 6) + xq] = a0 * s0 + (beta[o0] - mean[o0] * s0);
    enc[(b * 100 + o1) * 4096 + (y << 6) + xq] = a1 * s1 + (beta[o1] - mean[o1] * s1);
}

// ---------------- K3: pixel-shuffle + softmax over 25 ----------------
// enc [2,100,4096] fp32 -> Wsm [b][g][k][4096] fp32, g = ph*2+pw, channel = k*4+g
__global__ void k3_softmax(const float* __restrict__ enc, float* __restrict__ Wsm) {
    int t = blockIdx.x * 256 + threadIdx.x;     // 32768 threads
    int pos = t & 4095;
    int g   = (t >> 12) & 3;
    int b   = t >> 14;
    const float* e = enc + b * (100 * 4096) + g * 4096 + pos;
    float v[25];
    float mx = -1e30f;
    #pragma unroll
    for (int k = 0; k < 25; ++k) { v[k] = e[k * 4 * 4096]; mx = fmaxf(mx, v[k]); }
    float s = 0.f;
    #pragma unroll
    for (int k = 0; k < 25; ++k) { v[k] = __expf(v[k] - mx); s += v[k]; }
    float inv = 1.f / s;
    float* o = Wsm + ((b * 4 + g) * 25) * 4096 + pos;
    #pragma unroll
    for (int k = 0; k < 25; ++k) o[k * 4096] = v[k] * inv;
}

// ---------------- K4: weighted gather ----------------
// out[b,c,2yl+ph,2xl+pw] = sum_{i,j} W[b,g,i*5+j,yl,xl] * x[b,c,yl+i-2,xl+j-2]
// Block: one 8x8 low-res tile (= 16x16 out pixels = 256 threads), 32 channels.
__global__ void k4_gather(const float* __restrict__ x, const float* __restrict__ Wsm,
                          float* __restrict__ out) {
    __shared__ float4 patch[12 * 13];           // 12x12 used, stride 13 float4s
    int tile   = blockIdx.x;                     // 0..63
    int cchunk = blockIdx.y;                     // 0..7 (32 ch each)
    int b      = blockIdx.z;
    int ty0 = (tile >> 3) << 3;
    int tx0 = (tile & 7) << 3;
    int t   = threadIdx.x;
    int Yl = t >> 4, Xl = t & 15;                // out-pixel within 16x16 tile
    int ph = Yl & 1, pw = Xl & 1;
    int yl = ty0 + (Yl >> 1), xl = tx0 + (Xl >> 1);
    int g  = ph * 2 + pw;
    // per-thread softmax weights (constant across channels)
    float wreg[25];
    const float* wp = Wsm + ((b * 4 + g) * 25) * 4096 + yl * 64 + xl;
    #pragma unroll
    for (int k = 0; k < 25; ++k) wreg[k] = wp[k * 4096];
    // staging coords (threads 0..143)
    int pr = t / 12, pc = t % 12;
    int gy = ty0 - 2 + pr, gx = tx0 - 2 + pc;
    bool inb = (t < 144) && (gy >= 0) && (gy < 64) && (gx >= 0) && (gx < 64);
    int ly = Yl >> 1, lx = Xl >> 1;              // 0..7 local low-res coords
    for (int cg = 0; cg < 8; ++cg) {
        int c0 = cchunk * 32 + cg * 4;
        if (t < 144) {
            float4 v = {0.f, 0.f, 0.f, 0.f};
            if (inb) {
                const float* xp = x + ((b * 256 + c0) * 4096) + gy * 64 + gx;
                v.x = xp[0];
                v.y = xp[4096];
                v.z = xp[8192];
                v.w = xp[12288];
            }
            patch[pr * 13 + pc] = v;
        }
        __syncthreads();
        float4 acc = {0.f, 0.f, 0.f, 0.f};
        #pragma unroll
        for (int i = 0; i < 5; ++i) {
            #pragma unroll
            for (int j = 0; j < 5; ++j) {
                float4 xv = patch[(ly + i) * 13 + (lx + j)];
                float wv = wreg[i * 5 + j];
                acc.x += wv * xv.x; acc.y += wv * xv.y;
                acc.z += wv * xv.z; acc.w += wv * xv.w;
            }
        }
        float* op = out + ((b * 256 + c0) * 16384) + (2 * ty0 + Yl) * 128 + (2 * tx0 + Xl);
        op[0]     = acc.x;
        op[16384] = acc.y;
        op[32768] = acc.z;
        op[49152] = acc.w;
        __syncthreads();
    }
}

extern "C" void kernel_launch(void* const* d_in, const int* in_sizes, int n_in,
                              void* d_out, int out_size, void* d_ws, size_t ws_size,
                              hipStream_t stream) {
    const float* x          = (const float*)d_in[0];
    const float* comp_w     = (const float*)d_in[1];
    const float* comp_gamma = (const float*)d_in[2];
    const float* comp_beta  = (const float*)d_in[3];
    const float* comp_mean  = (const float*)d_in[4];
    const float* comp_var   = (const float*)d_in[5];
    const float* enc_w      = (const float*)d_in[6];
    const float* enc_gamma  = (const float*)d_in[7];
    const float* enc_beta   = (const float*)d_in[8];
    const float* enc_mean   = (const float*)d_in[9];
    const float* enc_var    = (const float*)d_in[10];
    float* out = (float*)d_out;

    float* ws   = (float*)d_ws;
    float* comp = ws;                           // 2*64*4096   = 524288 floats
    float* enc  = ws + 524288;                  // 2*100*4096  = 819200 floats
    float* Wsm  = ws + 524288 + 819200;         // 2*4*25*4096 = 819200 floats

    k1_comp<<<dim3(256), dim3(256), 0, stream>>>(x, comp_w, comp_gamma, comp_beta,
                                                 comp_mean, comp_var, comp);
    k2_enc<<<dim3(1600), dim3(256), 0, stream>>>(comp, enc_w, enc_gamma, enc_beta,
                                                 enc_mean, enc_var, enc);
    k3_softmax<<<dim3(128), dim3(256), 0, stream>>>(enc, Wsm);
    k4_gather<<<dim3(64, 8, 2), dim3(256), 0, stream>>>(x, Wsm, out);
}

// Round 3
// 217.510 us; speedup vs baseline: 1.1172x; 1.1172x over previous
//
#include <hip/hip_runtime.h>
#include <hip/hip_bf16.h>

#define EPSF 1e-5f

// ---------------- K1: comp = relu(bn(conv1x1(x))) ----------------
// x [2,256,4096] fp32 -> comp [2,64,4096] fp32. Thread: 1 pixel x 8 out channels.
__global__ void k1_comp(const float* __restrict__ x, const float* __restrict__ w,
                        const float* __restrict__ gamma, const float* __restrict__ beta,
                        const float* __restrict__ mean, const float* __restrict__ var,
                        float* __restrict__ comp) {
    int t = blockIdx.x * 256 + threadIdx.x;     // 65536 threads total
    int p  = t & 4095;
    int mq = (t >> 12) & 7;
    int b  = t >> 15;
    int m0 = mq * 8;
    const float* xb = x + b * (256 * 4096) + p;
    float acc[8] = {0.f, 0.f, 0.f, 0.f, 0.f, 0.f, 0.f, 0.f};
    #pragma unroll 16
    for (int c = 0; c < 256; ++c) {
        float xv = xb[c << 12];
        #pragma unroll
        for (int m = 0; m < 8; ++m)
            acc[m] += xv * w[(m0 + m) * 256 + c];
    }
    #pragma unroll
    for (int m = 0; m < 8; ++m) {
        int mo = m0 + m;
        float s = gamma[mo] * rsqrtf(var[mo] + EPSF);
        float r = acc[m] * s + (beta[mo] - mean[mo] * s);
        comp[(b * 64 + mo) * 4096 + p] = fmaxf(r, 0.f);
    }
}

// ---------------- K2: enc = bn(conv3x3(comp)) ----------------
// LDS-tiled: block = 16x16 pixel tile x 10 output channels. comp staged in
// 16-channel chunks as 18x18 halo planes; weights via scalar cache (uniform).
__global__ void k2_enc(const float* __restrict__ comp, const float* __restrict__ w,
                       const float* __restrict__ gamma, const float* __restrict__ beta,
                       const float* __restrict__ mean, const float* __restrict__ var,
                       float* __restrict__ enc) {
    __shared__ float sh[16 * 18 * 18];          // 16 ic-planes of 18x18 = 20736 B
    const int tile = blockIdx.x;                // 0..15 (4x4 tiles of 16x16)
    const int og   = blockIdx.y;                // 0..9  (10 out channels each)
    const int b    = blockIdx.z;
    const int ty0 = (tile >> 2) << 4;
    const int tx0 = (tile & 3) << 4;
    const int tid = threadIdx.x;
    const int tx = tid & 15, ty = tid >> 4;
    const int o0 = og * 10;

    float acc[10];
    #pragma unroll
    for (int i = 0; i < 10; ++i) acc[i] = 0.f;

    const float* cb = comp + b * (64 * 4096);
    for (int icc = 0; icc < 4; ++icc) {
        // stage 16 planes of 18x18 (halo -1..+16)
        for (int idx = tid; idx < 16 * 324; idx += 256) {
            int ic_l = idx / 324;
            int rem  = idx - ic_l * 324;
            int yy = rem / 18;
            int xx = rem - yy * 18;
            int gy = ty0 + yy - 1;
            int gx = tx0 + xx - 1;
            float v = 0.f;
            if (gy >= 0 && gy < 64 && gx >= 0 && gx < 64)
                v = cb[((icc * 16 + ic_l) << 12) + (gy << 6) + gx];
            sh[idx] = v;
        }
        __syncthreads();
        #pragma unroll 4
        for (int ic_l = 0; ic_l < 16; ++ic_l) {
            const float* base = sh + ic_l * 324 + ty * 18 + tx;
            float v[9];
            #pragma unroll
            for (int dy = 0; dy < 3; ++dy)
                #pragma unroll
                for (int dx = 0; dx < 3; ++dx)
                    v[dy * 3 + dx] = base[dy * 18 + dx];
            const int ic = icc * 16 + ic_l;
            #pragma unroll
            for (int o_l = 0; o_l < 10; ++o_l) {
                const float* wp = w + ((o0 + o_l) * 64 + ic) * 9;   // uniform -> s_load
                #pragma unroll
                for (int q = 0; q < 9; ++q)
                    acc[o_l] += wp[q] * v[q];
            }
        }
        __syncthreads();
    }
    const int pix = ((ty0 + ty) << 6) + tx0 + tx;
    #pragma unroll
    for (int o_l = 0; o_l < 10; ++o_l) {
        int o = o0 + o_l;
        float s = gamma[o] * rsqrtf(var[o] + EPSF);
        enc[(b * 100 + o) * 4096 + pix] = acc[o_l] * s + (beta[o] - mean[o] * s);
    }
}

// ---------------- K3: pixel-shuffle + softmax over 25 ----------------
__global__ void k3_softmax(const float* __restrict__ enc, float* __restrict__ Wsm) {
    int t = blockIdx.x * 256 + threadIdx.x;     // 32768 threads
    int pos = t & 4095;
    int g   = (t >> 12) & 3;
    int b   = t >> 14;
    const float* e = enc + b * (100 * 4096) + g * 4096 + pos;
    float v[25];
    float mx = -1e30f;
    #pragma unroll
    for (int k = 0; k < 25; ++k) { v[k] = e[k * 4 * 4096]; mx = fmaxf(mx, v[k]); }
    float s = 0.f;
    #pragma unroll
    for (int k = 0; k < 25; ++k) { v[k] = __expf(v[k] - mx); s += v[k]; }
    float inv = 1.f / s;
    float* o = Wsm + ((b * 4 + g) * 25) * 4096 + pos;
    #pragma unroll
    for (int k = 0; k < 25; ++k) o[k * 4096] = v[k] * inv;
}

// ---------------- K4: weighted gather ----------------
// Block: 16x8 low-res tile x 2 ph halves (256 threads). Thread owns (yl,xl,ph),
// both pw subpixels: 50 weight regs reused over 8 channel-quads. float2 stores.
__global__ void k4_gather(const float* __restrict__ x, const float* __restrict__ Wsm,
                          float* __restrict__ out) {
    __shared__ float4 patch[12 * 21];           // 12x20 used, pitch 21
    const int tile   = blockIdx.x;              // 0..31: tileY 0..7, tileX 0..3
    const int cchunk = blockIdx.y;              // 0..7 (32 channels each)
    const int b      = blockIdx.z;
    const int ly0 = (tile >> 2) << 3;           // lowres tile origin y (8 tall)
    const int lx0 = (tile & 3) << 4;            // lowres tile origin x (16 wide)
    const int tid = threadIdx.x;
    const int ph = tid >> 7;                    // 0..1
    const int r  = tid & 127;
    const int ly = r >> 4, lx = r & 15;         // 0..7, 0..15
    const int yl = ly0 + ly, xl = lx0 + lx;

    // 2x25 softmax weights (g = ph*2 + pw), constant across channels
    float w0[25], w1[25];
    {
        const float* wp0 = Wsm + ((b * 4 + ph * 2    ) * 25) * 4096 + yl * 64 + xl;
        const float* wp1 = Wsm + ((b * 4 + ph * 2 + 1) * 25) * 4096 + yl * 64 + xl;
        #pragma unroll
        for (int k = 0; k < 25; ++k) { w0[k] = wp0[k * 4096]; w1[k] = wp1[k * 4096]; }
    }
    // staging coords (threads 0..239)
    const int pr = tid / 20, pc = tid % 20;
    const int gy = ly0 - 2 + pr, gx = lx0 - 2 + pc;
    const bool inb = (tid < 240) && (gy >= 0) && (gy < 64) && (gx >= 0) && (gx < 64);

    for (int cg = 0; cg < 8; ++cg) {
        const int c0 = cchunk * 32 + cg * 4;
        if (tid < 240) {
            float4 v = {0.f, 0.f, 0.f, 0.f};
            if (inb) {
                const float* xp = x + ((b * 256 + c0) * 4096) + gy * 64 + gx;
                v.x = xp[0]; v.y = xp[4096]; v.z = xp[8192]; v.w = xp[12288];
            }
            patch[pr * 21 + pc] = v;
        }
        __syncthreads();
        float4 a0 = {0.f, 0.f, 0.f, 0.f};
        float4 a1 = {0.f, 0.f, 0.f, 0.f};
        #pragma unroll
        for (int i = 0; i < 5; ++i) {
            #pragma unroll
            for (int j = 0; j < 5; ++j) {
                float4 xv = patch[(ly + i) * 21 + (lx + j)];
                float wa = w0[i * 5 + j], wb = w1[i * 5 + j];
                a0.x += wa * xv.x; a0.y += wa * xv.y; a0.z += wa * xv.z; a0.w += wa * xv.w;
                a1.x += wb * xv.x; a1.y += wb * xv.y; a1.z += wb * xv.z; a1.w += wb * xv.w;
            }
        }
        float* ob = out + (b * 256 + c0) * 16384 + (2 * yl + ph) * 128 + 2 * xl;
        float2 s0 = {a0.x, a1.x}; *(float2*)(ob)           = s0;
        float2 s1 = {a0.y, a1.y}; *(float2*)(ob + 16384)   = s1;
        float2 s2 = {a0.z, a1.z}; *(float2*)(ob + 32768)   = s2;
        float2 s3 = {a0.w, a1.w}; *(float2*)(ob + 49152)   = s3;
        __syncthreads();
    }
}

extern "C" void kernel_launch(void* const* d_in, const int* in_sizes, int n_in,
                              void* d_out, int out_size, void* d_ws, size_t ws_size,
                              hipStream_t stream) {
    const float* x          = (const float*)d_in[0];
    const float* comp_w     = (const float*)d_in[1];
    const float* comp_gamma = (const float*)d_in[2];
    const float* comp_beta  = (const float*)d_in[3];
    const float* comp_mean  = (const float*)d_in[4];
    const float* comp_var   = (const float*)d_in[5];
    const float* enc_w      = (const float*)d_in[6];
    const float* enc_gamma  = (const float*)d_in[7];
    const float* enc_beta   = (const float*)d_in[8];
    const float* enc_mean   = (const float*)d_in[9];
    const float* enc_var    = (const float*)d_in[10];
    float* out = (float*)d_out;

    float* ws   = (float*)d_ws;
    float* comp = ws;                           // 2*64*4096   = 524288 floats
    float* enc  = ws + 524288;                  // 2*100*4096  = 819200 floats
    float* Wsm  = ws + 524288 + 819200;         // 2*4*25*4096 = 819200 floats

    k1_comp<<<dim3(256), dim3(256), 0, stream>>>(x, comp_w, comp_gamma, comp_beta,
                                                 comp_mean, comp_var, comp);
    k2_enc<<<dim3(16, 10, 2), dim3(256), 0, stream>>>(comp, enc_w, enc_gamma, enc_beta,
                                                      enc_mean, enc_var, enc);
    k3_softmax<<<dim3(128), dim3(256), 0, stream>>>(enc, Wsm);
    k4_gather<<<dim3(32, 8, 2), dim3(256), 0, stream>>>(x, Wsm, out);
}

// Round 4
// 157.933 us; speedup vs baseline: 1.5386x; 1.3772x over previous
//
#include <hip/hip_runtime.h>
#include <hip/hip_bf16.h>

#define EPSF 1e-5f

// ---------------- K1: comp = relu(bn(conv1x1(x))) ----------------
// x [2,256,4096] fp32 -> comp [2,64,4096] fp32. Thread: 1 pixel x 4 out channels.
// 512 blocks -> 16 waves/CU (was 256 blocks / 4 waves/CU).
__global__ void k1_comp(const float* __restrict__ x, const float* __restrict__ w,
                        const float* __restrict__ gamma, const float* __restrict__ beta,
                        const float* __restrict__ mean, const float* __restrict__ var,
                        float* __restrict__ comp) {
    int t = blockIdx.x * 256 + threadIdx.x;     // 131072 threads total
    int p  = t & 4095;
    int mq = (t >> 12) & 15;
    int b  = t >> 16;
    int m0 = mq * 4;
    const float* xb = x + b * (256 * 4096) + p;
    float acc[4] = {0.f, 0.f, 0.f, 0.f};
    #pragma unroll 16
    for (int c = 0; c < 256; ++c) {
        float xv = xb[c << 12];
        #pragma unroll
        for (int m = 0; m < 4; ++m)
            acc[m] += xv * w[(m0 + m) * 256 + c];   // wave-uniform -> s_load
    }
    #pragma unroll
    for (int m = 0; m < 4; ++m) {
        int mo = m0 + m;
        float s = gamma[mo] * rsqrtf(var[mo] + EPSF);
        float r = acc[m] * s + (beta[mo] - mean[mo] * s);
        comp[(b * 64 + mo) * 4096 + p] = fmaxf(r, 0.f);
    }
}

// ---------------- K2: split-K conv3x3 partials ----------------
// Block = 16x16 pixel tile x 10 out channels x ONE 16-ic chunk (split-K over 4).
// Writes raw partial sums to encp[icc]; BN is folded into k3.
// Grid (16, 40, 2): y -> og = y>>2, icc = y&3. 1280 blocks, 20 waves/CU.
__global__ void k2_enc_part(const float* __restrict__ comp, const float* __restrict__ w,
                            float* __restrict__ encp) {
    __shared__ float sh[16 * 18 * 18];          // 16 ic-planes of 18x18 = 20736 B
    const int tile = blockIdx.x;                // 0..15 (4x4 tiles of 16x16)
    const int og   = blockIdx.y >> 2;           // 0..9  (10 out channels each)
    const int icc  = blockIdx.y & 3;            // 0..3  (16 input channels each)
    const int b    = blockIdx.z;
    const int ty0 = (tile >> 2) << 4;
    const int tx0 = (tile & 3) << 4;
    const int tid = threadIdx.x;
    const int tx = tid & 15, ty = tid >> 4;
    const int o0 = og * 10;

    // stage 16 planes of 18x18 (halo -1..+16)
    const float* cb = comp + b * (64 * 4096);
    for (int idx = tid; idx < 16 * 324; idx += 256) {
        int ic_l = idx / 324;
        int rem  = idx - ic_l * 324;
        int yy = rem / 18;
        int xx = rem - yy * 18;
        int gy = ty0 + yy - 1;
        int gx = tx0 + xx - 1;
        float v = 0.f;
        if (gy >= 0 && gy < 64 && gx >= 0 && gx < 64)
            v = cb[((icc * 16 + ic_l) << 12) + (gy << 6) + gx];
        sh[idx] = v;
    }
    __syncthreads();

    float acc[10];
    #pragma unroll
    for (int i = 0; i < 10; ++i) acc[i] = 0.f;

    #pragma unroll 4
    for (int ic_l = 0; ic_l < 16; ++ic_l) {
        const float* base = sh + ic_l * 324 + ty * 18 + tx;
        float v[9];
        #pragma unroll
        for (int dy = 0; dy < 3; ++dy)
            #pragma unroll
            for (int dx = 0; dx < 3; ++dx)
                v[dy * 3 + dx] = base[dy * 18 + dx];
        const int ic = icc * 16 + ic_l;
        #pragma unroll
        for (int o_l = 0; o_l < 10; ++o_l) {
            const float* wp = w + ((o0 + o_l) * 64 + ic) * 9;   // uniform -> s_load
            #pragma unroll
            for (int q = 0; q < 9; ++q)
                acc[o_l] += wp[q] * v[q];
        }
    }
    const int pix = ((ty0 + ty) << 6) + tx0 + tx;
    #pragma unroll
    for (int o_l = 0; o_l < 10; ++o_l)
        encp[((icc * 2 + b) * 100 + o0 + o_l) * 4096 + pix] = acc[o_l];
}

// ---------------- K3: sum partials + BN + pixel-shuffle + softmax ----------------
// encp[4][2][100][4096] -> Wsm [b][g][k][4096], g = ph*2+pw, channel = k*4+g
__global__ void k3_softmax(const float* __restrict__ encp,
                           const float* __restrict__ gamma, const float* __restrict__ beta,
                           const float* __restrict__ mean, const float* __restrict__ var,
                           float* __restrict__ Wsm) {
    int t = blockIdx.x * 256 + threadIdx.x;     // 32768 threads
    int pos = t & 4095;
    int g   = (t >> 12) & 3;
    int b   = t >> 14;
    float v[25];
    float mx = -1e30f;
    #pragma unroll
    for (int k = 0; k < 25; ++k) {
        int o = k * 4 + g;                       // wave-uniform -> s_loads for BN
        float a = 0.f;
        #pragma unroll
        for (int icc = 0; icc < 4; ++icc)
            a += encp[((icc * 2 + b) * 100 + o) * 4096 + pos];
        float s = gamma[o] * rsqrtf(var[o] + EPSF);
        v[k] = a * s + (beta[o] - mean[o] * s);
        mx = fmaxf(mx, v[k]);
    }
    float s = 0.f;
    #pragma unroll
    for (int k = 0; k < 25; ++k) { v[k] = __expf(v[k] - mx); s += v[k]; }
    float inv = 1.f / s;
    float* o = Wsm + ((b * 4 + g) * 25) * 4096 + pos;
    #pragma unroll
    for (int k = 0; k < 25; ++k) o[k * 4096] = v[k] * inv;
}

// ---------------- K4: weighted gather ----------------
// Block: 16x8 low-res tile x 2 ph halves (256 threads). Thread owns (yl,xl,ph),
// both pw subpixels: 50 weight regs reused over 4 channel-quads. float2 stores.
// Grid.y = 16 (16 channels per block) -> 1024 blocks, 4 blocks/CU.
__global__ void k4_gather(const float* __restrict__ x, const float* __restrict__ Wsm,
                          float* __restrict__ out) {
    __shared__ float4 patch[12 * 21];           // 12x20 used, pitch 21
    const int tile   = blockIdx.x;              // 0..31: tileY 0..7, tileX 0..3
    const int cchunk = blockIdx.y;              // 0..15 (16 channels each)
    const int b      = blockIdx.z;
    const int ly0 = (tile >> 2) << 3;           // lowres tile origin y (8 tall)
    const int lx0 = (tile & 3) << 4;            // lowres tile origin x (16 wide)
    const int tid = threadIdx.x;
    const int ph = tid >> 7;                    // 0..1
    const int r  = tid & 127;
    const int ly = r >> 4, lx = r & 15;         // 0..7, 0..15
    const int yl = ly0 + ly, xl = lx0 + lx;

    // 2x25 softmax weights (g = ph*2 + pw), constant across channels
    float w0[25], w1[25];
    {
        const float* wp0 = Wsm + ((b * 4 + ph * 2    ) * 25) * 4096 + yl * 64 + xl;
        const float* wp1 = Wsm + ((b * 4 + ph * 2 + 1) * 25) * 4096 + yl * 64 + xl;
        #pragma unroll
        for (int k = 0; k < 25; ++k) { w0[k] = wp0[k * 4096]; w1[k] = wp1[k * 4096]; }
    }
    // staging coords (threads 0..239)
    const int pr = tid / 20, pc = tid % 20;
    const int gy = ly0 - 2 + pr, gx = lx0 - 2 + pc;
    const bool inb = (tid < 240) && (gy >= 0) && (gy < 64) && (gx >= 0) && (gx < 64);

    for (int cg = 0; cg < 4; ++cg) {
        const int c0 = cchunk * 16 + cg * 4;
        if (tid < 240) {
            float4 v = {0.f, 0.f, 0.f, 0.f};
            if (inb) {
                const float* xp = x + ((b * 256 + c0) * 4096) + gy * 64 + gx;
                v.x = xp[0]; v.y = xp[4096]; v.z = xp[8192]; v.w = xp[12288];
            }
            patch[pr * 21 + pc] = v;
        }
        __syncthreads();
        float4 a0 = {0.f, 0.f, 0.f, 0.f};
        float4 a1 = {0.f, 0.f, 0.f, 0.f};
        #pragma unroll
        for (int i = 0; i < 5; ++i) {
            #pragma unroll
            for (int j = 0; j < 5; ++j) {
                float4 xv = patch[(ly + i) * 21 + (lx + j)];
                float wa = w0[i * 5 + j], wb = w1[i * 5 + j];
                a0.x += wa * xv.x; a0.y += wa * xv.y; a0.z += wa * xv.z; a0.w += wa * xv.w;
                a1.x += wb * xv.x; a1.y += wb * xv.y; a1.z += wb * xv.z; a1.w += wb * xv.w;
            }
        }
        float* ob = out + (b * 256 + c0) * 16384 + (2 * yl + ph) * 128 + 2 * xl;
        float2 s0 = {a0.x, a1.x}; *(float2*)(ob)           = s0;
        float2 s1 = {a0.y, a1.y}; *(float2*)(ob + 16384)   = s1;
        float2 s2 = {a0.z, a1.z}; *(float2*)(ob + 32768)   = s2;
        float2 s3 = {a0.w, a1.w}; *(float2*)(ob + 49152)   = s3;
        __syncthreads();
    }
}

extern "C" void kernel_launch(void* const* d_in, const int* in_sizes, int n_in,
                              void* d_out, int out_size, void* d_ws, size_t ws_size,
                              hipStream_t stream) {
    const float* x          = (const float*)d_in[0];
    const float* comp_w     = (const float*)d_in[1];
    const float* comp_gamma = (const float*)d_in[2];
    const float* comp_beta  = (const float*)d_in[3];
    const float* comp_mean  = (const float*)d_in[4];
    const float* comp_var   = (const float*)d_in[5];
    const float* enc_w      = (const float*)d_in[6];
    const float* enc_gamma  = (const float*)d_in[7];
    const float* enc_beta   = (const float*)d_in[8];
    const float* enc_mean   = (const float*)d_in[9];
    const float* enc_var    = (const float*)d_in[10];
    float* out = (float*)d_out;

    float* ws   = (float*)d_ws;
    float* comp = ws;                           // 2*64*4096     =   524288 floats
    float* encp = ws + 524288;                  // 4*2*100*4096  =  3276800 floats
    float* Wsm  = ws + 524288 + 3276800;        // 2*4*25*4096   =   819200 floats
                                                // total 18.5 MB

    k1_comp<<<dim3(512), dim3(256), 0, stream>>>(x, comp_w, comp_gamma, comp_beta,
                                                 comp_mean, comp_var, comp);
    k2_enc_part<<<dim3(16, 40, 2), dim3(256), 0, stream>>>(comp, enc_w, encp);
    k3_softmax<<<dim3(128), dim3(256), 0, stream>>>(encp, enc_gamma, enc_beta,
                                                    enc_mean, enc_var, Wsm);
    k4_gather<<<dim3(32, 16, 2), dim3(256), 0, stream>>>(x, Wsm, out);
}

// Round 5
// 157.119 us; speedup vs baseline: 1.5466x; 1.0052x over previous
//
#include <hip/hip_runtime.h>
#include <hip/hip_bf16.h>

typedef __hip_bfloat16 bf16;
#define EPSF 1e-5f

// ---------------- K1: comp = relu(bn(conv1x1(x))) ----------------
// Block = 64-px tile x 32 oc (4 waves; wave = 8 wave-uniform oc x 64 px).
// x staged via double-buffered LDS chunks of 32ic x 64px (coalesced float4):
// each (px,ic) is read once per ocg -> x traffic 134 MB -> 16.8 MB.
// Grid (64, 2, 2) = 256 blocks.
__global__ void k1_comp(const float* __restrict__ x, const float* __restrict__ w,
                        const float* __restrict__ gamma, const float* __restrict__ beta,
                        const float* __restrict__ mean, const float* __restrict__ var,
                        float* __restrict__ comp) {
    __shared__ float shx[2][32 * 64];           // 16 KB
    const int pxt = blockIdx.x;                 // 0..63
    const int ocg = blockIdx.y;                 // 0..1
    const int b   = blockIdx.z;
    const int tid  = threadIdx.x;
    const int wave = tid >> 6, lane = tid & 63;
    const int oc0 = ocg * 32 + wave * 8;        // wave-uniform
    const int px0 = pxt << 6;
    const float* xb = x + b * (256 * 4096) + px0;

    float acc[8] = {0.f, 0.f, 0.f, 0.f, 0.f, 0.f, 0.f, 0.f};

    // stage chunk 0
    #pragma unroll
    for (int i = 0; i < 2; ++i) {
        int f4  = tid * 2 + i;                  // 0..511
        int row = f4 >> 4, col4 = f4 & 15;
        float4 v = *(const float4*)(xb + row * 4096 + col4 * 4);
        *(float4*)(&shx[0][row * 64 + col4 * 4]) = v;
    }
    __syncthreads();

    for (int icc = 0; icc < 8; ++icc) {
        const int buf = icc & 1;
        if (icc < 7) {
            #pragma unroll
            for (int i = 0; i < 2; ++i) {
                int f4  = tid * 2 + i;
                int row = f4 >> 4, col4 = f4 & 15;
                float4 v = *(const float4*)(xb + ((icc + 1) * 32 + row) * 4096 + col4 * 4);
                *(float4*)(&shx[buf ^ 1][row * 64 + col4 * 4]) = v;
            }
        }
        #pragma unroll 8
        for (int ic_l = 0; ic_l < 32; ++ic_l) {
            float xv = shx[buf][ic_l * 64 + lane];
            const float* wp = w + icc * 32 + ic_l;      // + oc*256, uniform -> s_load
            #pragma unroll
            for (int m = 0; m < 8; ++m)
                acc[m] += xv * wp[(oc0 + m) * 256];
        }
        __syncthreads();
    }
    #pragma unroll
    for (int m = 0; m < 8; ++m) {
        int mo = oc0 + m;
        float s = gamma[mo] * rsqrtf(var[mo] + EPSF);
        float r = acc[m] * s + (beta[mo] - mean[mo] * s);
        comp[(b * 64 + mo) * 4096 + px0 + lane] = fmaxf(r, 0.f);
    }
}

// ---------------- K2: split-K conv3x3 partials ----------------
// Block = 16x16 pixel tile x 10 out channels x ONE 16-ic chunk (split-K over 4).
// Writes raw partial sums to encp[icc]; BN is folded into k3.
__global__ void k2_enc_part(const float* __restrict__ comp, const float* __restrict__ w,
                            float* __restrict__ encp) {
    __shared__ float sh[16 * 18 * 18];          // 16 ic-planes of 18x18 = 20736 B
    const int tile = blockIdx.x;                // 0..15 (4x4 tiles of 16x16)
    const int og   = blockIdx.y >> 2;           // 0..9  (10 out channels each)
    const int icc  = blockIdx.y & 3;            // 0..3  (16 input channels each)
    const int b    = blockIdx.z;
    const int ty0 = (tile >> 2) << 4;
    const int tx0 = (tile & 3) << 4;
    const int tid = threadIdx.x;
    const int tx = tid & 15, ty = tid >> 4;
    const int o0 = og * 10;

    const float* cb = comp + b * (64 * 4096);
    for (int idx = tid; idx < 16 * 324; idx += 256) {
        int ic_l = idx / 324;
        int rem  = idx - ic_l * 324;
        int yy = rem / 18;
        int xx = rem - yy * 18;
        int gy = ty0 + yy - 1;
        int gx = tx0 + xx - 1;
        float v = 0.f;
        if (gy >= 0 && gy < 64 && gx >= 0 && gx < 64)
            v = cb[((icc * 16 + ic_l) << 12) + (gy << 6) + gx];
        sh[idx] = v;
    }
    __syncthreads();

    float acc[10];
    #pragma unroll
    for (int i = 0; i < 10; ++i) acc[i] = 0.f;

    #pragma unroll 4
    for (int ic_l = 0; ic_l < 16; ++ic_l) {
        const float* base = sh + ic_l * 324 + ty * 18 + tx;
        float v[9];
        #pragma unroll
        for (int dy = 0; dy < 3; ++dy)
            #pragma unroll
            for (int dx = 0; dx < 3; ++dx)
                v[dy * 3 + dx] = base[dy * 18 + dx];
        const int ic = icc * 16 + ic_l;
        #pragma unroll
        for (int o_l = 0; o_l < 10; ++o_l) {
            const float* wp = w + ((o0 + o_l) * 64 + ic) * 9;   // uniform -> s_load
            #pragma unroll
            for (int q = 0; q < 9; ++q)
                acc[o_l] += wp[q] * v[q];
        }
    }
    const int pix = ((ty0 + ty) << 6) + tx0 + tx;
    #pragma unroll
    for (int o_l = 0; o_l < 10; ++o_l)
        encp[((icc * 2 + b) * 100 + o0 + o_l) * 4096 + pix] = acc[o_l];
}

// ---------------- K3: sum partials + BN + pixel-shuffle + softmax (bf16 out) ----
__global__ void k3_softmax(const float* __restrict__ encp,
                           const float* __restrict__ gamma, const float* __restrict__ beta,
                           const float* __restrict__ mean, const float* __restrict__ var,
                           bf16* __restrict__ Wsm) {
    int t = blockIdx.x * 256 + threadIdx.x;     // 32768 threads
    int pos = t & 4095;
    int g   = (t >> 12) & 3;
    int b   = t >> 14;
    float v[25];
    float mx = -1e30f;
    #pragma unroll
    for (int k = 0; k < 25; ++k) {
        int o = k * 4 + g;                       // wave-uniform -> s_loads for BN
        float a = 0.f;
        #pragma unroll
        for (int icc = 0; icc < 4; ++icc)
            a += encp[((icc * 2 + b) * 100 + o) * 4096 + pos];
        float s = gamma[o] * rsqrtf(var[o] + EPSF);
        v[k] = a * s + (beta[o] - mean[o] * s);
        mx = fmaxf(mx, v[k]);
    }
    float s = 0.f;
    #pragma unroll
    for (int k = 0; k < 25; ++k) { v[k] = __expf(v[k] - mx); s += v[k]; }
    float inv = 1.f / s;
    bf16* o = Wsm + ((b * 4 + g) * 25) * 4096 + pos;
    #pragma unroll
    for (int k = 0; k < 25; ++k) o[k * 4096] = __float2bfloat16(v[k] * inv);
}

// ---------------- K4: weighted gather ----------------
// Block: 16x8 low-res tile x 2 ph halves (256 threads). Thread owns (yl,xl,ph),
// both pw subpixels: 50 bf16 weight regs reused over 4 channel-quads.
__global__ void k4_gather(const float* __restrict__ x, const bf16* __restrict__ Wsm,
                          float* __restrict__ out) {
    __shared__ float4 patch[12 * 21];           // 12x20 used, pitch 21
    const int tile   = blockIdx.x;              // 0..31: tileY 0..7, tileX 0..3
    const int cchunk = blockIdx.y;              // 0..15 (16 channels each)
    const int b      = blockIdx.z;
    const int ly0 = (tile >> 2) << 3;
    const int lx0 = (tile & 3) << 4;
    const int tid = threadIdx.x;
    const int ph = tid >> 7;
    const int r  = tid & 127;
    const int ly = r >> 4, lx = r & 15;
    const int yl = ly0 + ly, xl = lx0 + lx;

    float w0[25], w1[25];
    {
        const bf16* wp0 = Wsm + ((b * 4 + ph * 2    ) * 25) * 4096 + yl * 64 + xl;
        const bf16* wp1 = Wsm + ((b * 4 + ph * 2 + 1) * 25) * 4096 + yl * 64 + xl;
        #pragma unroll
        for (int k = 0; k < 25; ++k) {
            w0[k] = __bfloat162float(wp0[k * 4096]);
            w1[k] = __bfloat162float(wp1[k * 4096]);
        }
    }
    const int pr = tid / 20, pc = tid % 20;
    const int gy = ly0 - 2 + pr, gx = lx0 - 2 + pc;
    const bool inb = (tid < 240) && (gy >= 0) && (gy < 64) && (gx >= 0) && (gx < 64);

    for (int cg = 0; cg < 4; ++cg) {
        const int c0 = cchunk * 16 + cg * 4;
        if (tid < 240) {
            float4 v = {0.f, 0.f, 0.f, 0.f};
            if (inb) {
                const float* xp = x + ((b * 256 + c0) * 4096) + gy * 64 + gx;
                v.x = xp[0]; v.y = xp[4096]; v.z = xp[8192]; v.w = xp[12288];
            }
            patch[pr * 21 + pc] = v;
        }
        __syncthreads();
        float4 a0 = {0.f, 0.f, 0.f, 0.f};
        float4 a1 = {0.f, 0.f, 0.f, 0.f};
        #pragma unroll
        for (int i = 0; i < 5; ++i) {
            #pragma unroll
            for (int j = 0; j < 5; ++j) {
                float4 xv = patch[(ly + i) * 21 + (lx + j)];
                float wa = w0[i * 5 + j], wb = w1[i * 5 + j];
                a0.x += wa * xv.x; a0.y += wa * xv.y; a0.z += wa * xv.z; a0.w += wa * xv.w;
                a1.x += wb * xv.x; a1.y += wb * xv.y; a1.z += wb * xv.z; a1.w += wb * xv.w;
            }
        }
        float* ob = out + (b * 256 + c0) * 16384 + (2 * yl + ph) * 128 + 2 * xl;
        float2 s0 = {a0.x, a1.x}; *(float2*)(ob)           = s0;
        float2 s1 = {a0.y, a1.y}; *(float2*)(ob + 16384)   = s1;
        float2 s2 = {a0.z, a1.z}; *(float2*)(ob + 32768)   = s2;
        float2 s3 = {a0.w, a1.w}; *(float2*)(ob + 49152)   = s3;
        __syncthreads();
    }
}

extern "C" void kernel_launch(void* const* d_in, const int* in_sizes, int n_in,
                              void* d_out, int out_size, void* d_ws, size_t ws_size,
                              hipStream_t stream) {
    const float* x          = (const float*)d_in[0];
    const float* comp_w     = (const float*)d_in[1];
    const float* comp_gamma = (const float*)d_in[2];
    const float* comp_beta  = (const float*)d_in[3];
    const float* comp_mean  = (const float*)d_in[4];
    const float* comp_var   = (const float*)d_in[5];
    const float* enc_w      = (const float*)d_in[6];
    const float* enc_gamma  = (const float*)d_in[7];
    const float* enc_beta   = (const float*)d_in[8];
    const float* enc_mean   = (const float*)d_in[9];
    const float* enc_var    = (const float*)d_in[10];
    float* out = (float*)d_out;

    float* ws   = (float*)d_ws;
    float* comp = ws;                           // 2*64*4096     =   524288 floats
    float* encp = ws + 524288;                  // 4*2*100*4096  =  3276800 floats
    bf16*  Wsm  = (bf16*)(ws + 524288 + 3276800); // 2*4*25*4096 bf16 = 409600 floats-equiv

    k1_comp<<<dim3(64, 2, 2), dim3(256), 0, stream>>>(x, comp_w, comp_gamma, comp_beta,
                                                      comp_mean, comp_var, comp);
    k2_enc_part<<<dim3(16, 40, 2), dim3(256), 0, stream>>>(comp, enc_w, encp);
    k3_softmax<<<dim3(128), dim3(256), 0, stream>>>(encp, enc_gamma, enc_beta,
                                                    enc_mean, enc_var, Wsm);
    k4_gather<<<dim3(32, 16, 2), dim3(256), 0, stream>>>(x, Wsm, out);
}